// Round 5
// baseline (360.444 us; speedup 1.0000x reference)
//
#include <hip/hip_runtime.h>
#include <hip/hip_bf16.h>
#include <stdint.h>

#define DFEAT 256
#define NPTS  8192

typedef __attribute__((ext_vector_type(8)))  short bf16x8;   // 8 bf16 = 4 VGPRs
typedef __attribute__((ext_vector_type(16))) float f32x16;   // 32x32 C/D
typedef __attribute__((ext_vector_type(4)))  int   int4v;
typedef __attribute__((ext_vector_type(4)))  float f32x4;

#define AS1 __attribute__((address_space(1)))
#define AS3 __attribute__((address_space(3)))

__device__ inline void dma16(const void* g, void* l) {
  // async global->LDS, 16B/lane; LDS dest = wave-uniform base + lane*16
  __builtin_amdgcn_global_load_lds((const AS1 uint32_t*)g, (AS3 uint32_t*)l, 16, 0, 0);
}

__device__ inline uint16_t f2bf(float f) {  // RNE fp32->bf16
  union { float f; uint32_t u; } v; v.f = f;
  return (uint16_t)((v.u + 0x7FFFu + ((v.u >> 16) & 1u)) >> 16);
}

// ---------------------------------------------------------------------------
// ws fragment layouts (written by ms_combine):
//  xaf: per 32-point block nb, chunk s=2*ks+g, lane 0..31:
//       X[d = s*8 .. +8][pt = nb*32+lane]  (A/B-frag order, k=d)
//       byte addr = nb*16384 + s*512 + lane*16.     (4 MB)
//  xbf: per 32-d block db, chunk u (n/8), lane:
//       X[d = db*32+lane][n = u*8 .. +8]   (PV A-frag order, k=n)
//       byte addr = db*524288 + u*512 + lane*16.    (4 MB)
// xaf's n-tile slice [j*32768, +32768) is DMA'd to LDS as an IDENTITY copy:
// lane-major inner layout -> wave-contiguous DMA and conflict-free ds_reads.
// ---------------------------------------------------------------------------

// Fused mean-shift step. Per WG: m-tile 64, 32 consecutive n-tiles of 64.
//   S[n,m] = Xn^T Xm (A from double-buffered LDS stage, B resident regs)
//   P = exp(6S) -> LDS Ps ; CS[m] += colsum ; O[d,m] += Xn P (A from xbf regs)
// DMA(t+1) issued right after top barrier -> flies across S(t) before the
// mid-barrier vmcnt drain. grid = 128 m-tiles x 4 n-splits = 512 = 2 WG/CU.
//
// R5 delta (R4 showed FETCH -58% and VALU -5pp with FLAT time -> neither
// fetch volume nor VALU count is the pole; suspect serial MFMA dep chain):
//  - S accumulation split into 4 round-robin partials (sp0..sp3), merged in
//    the exp phase. Serial MFMA chain 16 -> 4. acc regs 80 -> 128 (+VGPR 108
//    = 236 <= 256, still 2 waves/SIMD).
// Kept from R4: v_cvt_pk_bf16_f32 packing; XCD-pair blockIdx swizzle.
__global__ __launch_bounds__(256, 2) void ms_fused(
    const uint16_t* __restrict__ xaf,
    const uint16_t* __restrict__ xbf,
    float* __restrict__ num,           // [256][8192] fp32, pre-zeroed
    float* __restrict__ cs)            // [8192] fp32, pre-zeroed
{
  __shared__ __attribute__((aligned(16))) uint16_t XT[2][16384];  // 2x32KB stage
  __shared__ __attribute__((aligned(16))) uint16_t Ps[64 * 64];   // 8KB swizzled

  const int tid  = threadIdx.x;
  const int w    = tid >> 6;
  const int lane = tid & 63;
  const int l31  = lane & 31;
  const int g    = lane >> 5;
  const int bid  = blockIdx.x;
  const int mt   = (bid & 1) | ((bid >> 3) << 1);   // 0..127
  const int q    = (bid >> 1) & 3;                  // n-split 0..3
  const int m0   = mt * 64;
  const int a_sub = w >> 1;                  // S n-sub (0/1)
  const int b_sub = w & 1;                   // S m-sub (0/1)

  const char* xafc = (const char*)xaf;
  const char* xbfc = (const char*)xbf;
  char*       Psc  = (char*)Ps;

  // Xm B-fragments resident (64 VGPRs), one-time coalesced load
  bf16x8 Bm[16];
  {
    const char* bp = xafc + (size_t)(m0 / 32 + b_sub) * 16384 + g * 512 + l31 * 16;
    #pragma unroll
    for (int ks = 0; ks < 16; ++ks)
      Bm[ks] = __builtin_bit_cast(bf16x8, *(const int4v*)(bp + ks * 1024));
  }

  f32x16 accO[2][2];
  #pragma unroll
  for (int i = 0; i < 2; ++i)
    #pragma unroll
    for (int j = 0; j < 2; ++j)
      #pragma unroll
      for (int r = 0; r < 16; ++r) accO[i][j][r] = 0.0f;
  float csacc = 0.0f;

  const int mloc = 32 * b_sub + l31;
  const int l7   = l31 & 7;
  const int j0   = q * 32;                   // first n-tile index

  // prologue: stage tile j0 into buf 0 (identity copy, 8x 16B per thread)
  {
    const char* src = xafc + (size_t)j0 * 32768;
    #pragma unroll
    for (int r = 0; r < 8; ++r)
      dma16(src + tid * 16 + r * 4096, (char*)XT[0] + tid * 16 + r * 4096);
  }

  for (int t = 0; t < 32; ++t) {
    const int jt  = j0 + t;
    const int cur = t & 1;
    __syncthreads();  // A: DMA(t) drained into XT[cur]; Ps writable (PV(t-1) done)

    // issue DMA(t+1) -> other buffer; flies across the whole S phase
    if (t < 31) {
      const char* src = xafc + (size_t)(jt + 1) * 32768;
      #pragma unroll
      for (int r = 0; r < 8; ++r)
        dma16(src + tid * 16 + r * 4096,
              (char*)XT[cur ^ 1] + tid * 16 + r * 4096);
    }

    // prefetch PV A-frags from global (coalesced 1KB wave loads, 32 VGPRs)
    const int n0 = jt * 64;
    bf16x8 Xf[2][4];
    #pragma unroll
    for (int t2 = 0; t2 < 2; ++t2) {
      const char* xp = xbfc + (size_t)(2 * w + t2) * 524288 +
                       (size_t)(n0 >> 3) * 512 + g * 512 + l31 * 16;
      #pragma unroll
      for (int ks = 0; ks < 4; ++ks)
        Xf[t2][ks] = __builtin_bit_cast(bf16x8, *(const int4v*)(xp + ks * 1024));
    }

    // ---- S = Xn^T Xm : 4 round-robin partial accumulators (dep chain 4) ----
    f32x16 sp0, sp1, sp2, sp3;
    #pragma unroll
    for (int r = 0; r < 16; ++r) { sp0[r] = 0.0f; sp1[r] = 0.0f;
                                   sp2[r] = 0.0f; sp3[r] = 0.0f; }
    {
      const char* ap = (const char*)XT[cur] + a_sub * 16384 + g * 512 + l31 * 16;
      #pragma unroll
      for (int ks = 0; ks < 4; ++ks) {
        bf16x8 A0 = __builtin_bit_cast(bf16x8, *(const int4v*)(ap + (4*ks+0) * 1024));
        bf16x8 A1 = __builtin_bit_cast(bf16x8, *(const int4v*)(ap + (4*ks+1) * 1024));
        bf16x8 A2 = __builtin_bit_cast(bf16x8, *(const int4v*)(ap + (4*ks+2) * 1024));
        bf16x8 A3 = __builtin_bit_cast(bf16x8, *(const int4v*)(ap + (4*ks+3) * 1024));
        sp0 = __builtin_amdgcn_mfma_f32_32x32x16_bf16(A0, Bm[4*ks+0], sp0, 0, 0, 0);
        sp1 = __builtin_amdgcn_mfma_f32_32x32x16_bf16(A1, Bm[4*ks+1], sp1, 0, 0, 0);
        sp2 = __builtin_amdgcn_mfma_f32_32x32x16_bf16(A2, Bm[4*ks+2], sp2, 0, 0, 0);
        sp3 = __builtin_amdgcn_mfma_f32_32x32x16_bf16(A3, Bm[4*ks+3], sp3, 0, 0, 0);
      }
    }

    // ---- P = exp(6S); colsum; pack to Ps (4 ds_write_b64, swizzled) ----
    // partial-merge folded in; v_cvt_pk_bf16_f32 (RNE, == manual f2bf)
    #pragma unroll
    for (int k = 0; k < 4; ++k) {
      float a0 = (sp0[4*k+0] + sp1[4*k+0]) + (sp2[4*k+0] + sp3[4*k+0]);
      float a1 = (sp0[4*k+1] + sp1[4*k+1]) + (sp2[4*k+1] + sp3[4*k+1]);
      float a2 = (sp0[4*k+2] + sp1[4*k+2]) + (sp2[4*k+2] + sp3[4*k+2]);
      float a3 = (sp0[4*k+3] + sp1[4*k+3]) + (sp2[4*k+3] + sp3[4*k+3]);
      float e0 = __expf(6.0f * a0);
      float e1 = __expf(6.0f * a1);
      float e2 = __expf(6.0f * a2);
      float e3 = __expf(6.0f * a3);
      csacc += (e0 + e1) + (e2 + e3);
      uint32_t lo, hi;
      asm("v_cvt_pk_bf16_f32 %0, %1, %2" : "=v"(lo) : "v"(e0), "v"(e1));
      asm("v_cvt_pk_bf16_f32 %0, %1, %2" : "=v"(hi) : "v"(e2), "v"(e3));
      int p = (4 * a_sub + k) ^ (mloc & 7);
      *(uint64_t*)(Psc + mloc * 128 + p * 16 + 8 * g) =
          ((uint64_t)hi << 32) | lo;
    }
    __syncthreads();  // B: Ps visible (also drains DMA(t+1)/Xf after ~S-phase)

    // ---- O[d,m] += Xn * P ----
    #pragma unroll
    for (int ks = 0; ks < 4; ++ks) {
      bf16x8 Bp[2];
      #pragma unroll
      for (int mm = 0; mm < 2; ++mm) {
        int mrow = 32 * mm + l31;
        int p = (2 * ks + g) ^ l7;
        Bp[mm] = __builtin_bit_cast(bf16x8,
            *(const int4v*)(Psc + mrow * 128 + p * 16));
      }
      #pragma unroll
      for (int t2 = 0; t2 < 2; ++t2) {
        accO[t2][0] = __builtin_amdgcn_mfma_f32_32x32x16_bf16(Xf[t2][ks], Bp[0], accO[t2][0], 0,0,0);
        accO[t2][1] = __builtin_amdgcn_mfma_f32_32x32x16_bf16(Xf[t2][ks], Bp[1], accO[t2][1], 0,0,0);
      }
    }
  }

  // ---- epilogue: merge partials ----
  csacc += __shfl_xor(csacc, 32, 64);
  if (g == 0) atomicAdd(&cs[m0 + mloc], csacc);
  #pragma unroll
  for (int t2 = 0; t2 < 2; ++t2)
    #pragma unroll
    for (int mm = 0; mm < 2; ++mm)
      #pragma unroll
      for (int r = 0; r < 16; ++r) {
        int drow = 32 * (2 * w + t2) + (r & 3) + 8 * (r >> 2) + 4 * g;
        int mg   = m0 + 32 * mm + l31;
        atomicAdd(&num[(size_t)drow * NPTS + mg], accO[t2][mm][r]);
      }
}

// ---------------------------------------------------------------------------
// Combine. mode1: v = num/cs -> yout; zero num after read; zero cs_next.
//          mode0: v = src (initial fp32 X). Both: emit xaf + xbf frags.
// float4-vectorized global traffic.
// ---------------------------------------------------------------------------
__global__ __launch_bounds__(256) void ms_combine(
    const float* __restrict__ src, const float* __restrict__ csr,
    float* __restrict__ csz, float* __restrict__ yout,
    float* __restrict__ numz,
    uint16_t* __restrict__ xaf, uint16_t* __restrict__ xbf,
    const int mode)
{
  __shared__ uint16_t T[64][66];
  const int tid = threadIdx.x;
  const int n0 = blockIdx.x * 64;
  const int d0 = blockIdx.y * 64;

  #pragma unroll
  for (int i = 0; i < 4; ++i) {
    int e  = tid + i * 256;              // float4 slot
    int dl = e >> 4, nq = e & 15;
    size_t idx = (size_t)(d0 + dl) * NPTS + (n0 + nq * 4);
    f32x4 v = *(const f32x4*)(src + idx);
    if (mode) {
      f32x4 c = *(const f32x4*)(csr + n0 + nq * 4);
      v /= c;
      *(f32x4*)(yout + idx) = v;
      f32x4 z = {0.f, 0.f, 0.f, 0.f};
      *(f32x4*)(numz + idx) = z;
    }
    #pragma unroll
    for (int k = 0; k < 4; ++k) T[dl][nq * 4 + k] = f2bf(v[k]);
  }
  if (mode && blockIdx.y == 0 && tid < 64) csz[n0 + tid] = 0.0f;
  __syncthreads();

  char* xafc = (char*)xaf;
  char* xbfc = (char*)xbf;
  // xaf chunks: (nb, s, lane) -> T[s*8 + j][nb*32+lane]
  #pragma unroll
  for (int i = 0; i < 2; ++i) {
    int c  = tid + i * 256;
    int nb = c >> 8, s2 = (c >> 5) & 7, ln = c & 31;
    union { uint32_t u[4]; int4v v; } pk;
    #pragma unroll
    for (int k = 0; k < 4; ++k) {
      uint32_t lo = T[s2 * 8 + 2 * k][nb * 32 + ln];
      uint32_t hi = T[s2 * 8 + 2 * k + 1][nb * 32 + ln];
      pk.u[k] = lo | (hi << 16);
    }
    *(int4v*)(xafc + (size_t)(n0 / 32 + nb) * 16384 +
              (size_t)(d0 / 8 + s2) * 512 + ln * 16) = pk.v;
  }
  // xbf chunks: (db, u, lane) -> T[db*32+lane][u*8 + j]  (row-contiguous)
  #pragma unroll
  for (int i = 0; i < 2; ++i) {
    int c  = tid + i * 256;
    int db = c >> 8, uu = (c >> 5) & 7, ln = c & 31;
    const uint16_t* tr = &T[db * 32 + ln][uu * 8];
    union { uint32_t u[4]; int4v v; } pk;
    #pragma unroll
    for (int k = 0; k < 4; ++k)
      pk.u[k] = (uint32_t)tr[2 * k] | ((uint32_t)tr[2 * k + 1] << 16);
    *(int4v*)(xbfc + (size_t)(d0 / 32 + db) * 524288 +
              (size_t)(n0 / 8 + uu) * 512 + ln * 16) = pk.v;
  }
}

extern "C" void kernel_launch(void* const* d_in, const int* in_sizes, int n_in,
                              void* d_out, int out_size, void* d_ws, size_t ws_size,
                              hipStream_t stream)
{
  (void)in_sizes; (void)n_in; (void)out_size; (void)ws_size;
  const float* X = (const float*)d_in[0];
  float* out = (float*)d_out;
  char* ws = (char*)d_ws;
  // ws: [0,4M) xaf ; [4M,8M) xbf ; [8M,16M) num ; [16M,+32K) cs0 ; [+32K) cs1
  uint16_t* xaf = (uint16_t*)(ws);
  uint16_t* xbf = (uint16_t*)(ws + (4u << 20));
  float*    num = (float*)   (ws + (8u << 20));
  float*    cs0 = (float*)   (ws + (16u << 20));
  float*    cs1 = (float*)   (ws + (16u << 20) + 32768);

  // zero num + both cs buffers once per call (ws is re-poisoned each call)
  hipMemsetAsync(ws + (8u << 20), 0, (8u << 20) + 65536, stream);

  dim3 cgrid(NPTS / 64, DFEAT / 64);
  ms_combine<<<cgrid, 256, 0, stream>>>(X, nullptr, nullptr, nullptr, nullptr,
                                        xaf, xbf, 0);
  for (int it = 0; it < 3; ++it) {
    float* csA = (it & 1) ? cs1 : cs0;
    float* csB = (it & 1) ? cs0 : cs1;
    ms_fused<<<512, 256, 0, stream>>>(xaf, xbf, num, csA);
    ms_combine<<<cgrid, 256, 0, stream>>>(num, csA, csB,
                                          out + (size_t)it * DFEAT * NPTS,
                                          num, xaf, xbf, 1);
  }
}

// Round 6
// 338.091 us; speedup vs baseline: 1.0661x; 1.0661x over previous
//
#include <hip/hip_runtime.h>
#include <hip/hip_bf16.h>
#include <stdint.h>

#define DFEAT 256
#define NPTS  8192

typedef __attribute__((ext_vector_type(8)))  short bf16x8;   // 8 bf16 = 4 VGPRs
typedef __attribute__((ext_vector_type(16))) float f32x16;   // 32x32 C/D
typedef __attribute__((ext_vector_type(4)))  int   int4v;
typedef __attribute__((ext_vector_type(4)))  float f32x4;

#define AS1 __attribute__((address_space(1)))
#define AS3 __attribute__((address_space(3)))

__device__ inline void dma16(const void* g, void* l) {
  // async global->LDS, 16B/lane; LDS dest = wave-uniform base + lane*16
  __builtin_amdgcn_global_load_lds((const AS1 uint32_t*)g, (AS3 uint32_t*)l, 16, 0, 0);
}

__device__ inline uint16_t f2bf(float f) {  // RNE fp32->bf16
  union { float f; uint32_t u; } v; v.f = f;
  return (uint16_t)((v.u + 0x7FFFu + ((v.u >> 16) & 1u)) >> 16);
}

// ---------------------------------------------------------------------------
// ws fragment layouts (written by ms_combine):
//  xaf: per 32-point block nb, chunk s=2*ks+g, lane 0..31:
//       X[d = s*8 .. +8][pt = nb*32+lane]  (A/B-frag order, k=d)
//       byte addr = nb*16384 + s*512 + lane*16.     (4 MB)
//  xbf: per 32-d block db, chunk u (n/8), lane:
//       X[d = db*32+lane][n = u*8 .. +8]   (PV A-frag order, k=n)
//       byte addr = db*524288 + u*512 + lane*16.    (4 MB)
// ---------------------------------------------------------------------------

// R6: SINGLE-BARRIER pipelined body. R0-R5 all ~95-101us regardless of
// schedule/occupancy/VALU/chain changes; accounting shows VALU+LDS+L2+MFMA
// SUM to the body time -> 2-barrier lockstep serializes the pipes (all waves
// in the same phase). New structure per body t (one s_barrier):
//   S(t) -> issue DMA(t+1) -> PV(t-1) [Ps dbuf] -> issue Xf(t) -> exp(t)
//   -> vmcnt(8)+lgkm(0); s_barrier
// FIFO: DMA(t+1) issued before Xf(t) (pinned by sched_barrier(0x38F), which
// blocks only VMEM crossing): PV(t-1) waits vmcnt(8) = Xf(t-1) done / DMA
// flying; barrier waits vmcnt(8) = DMA(t+1) done / Xf(t) flying. No vmcnt(0)
// in the loop. exp(t) VALU co-issues with PV(t-1) MFMA (T15), Ps round-trip
// off the serial path. LDS 80KB/WG (XT 2x32 + Ps 2x8) = 2 WG/CU exact.
// Kept from R4: cvt_pk bf16 packing, XCD-pair blockIdx swizzle, single s acc.
__global__ __launch_bounds__(256, 2) void ms_fused(
    const uint16_t* __restrict__ xaf,
    const uint16_t* __restrict__ xbf,
    float* __restrict__ num,           // [256][8192] fp32, pre-zeroed
    float* __restrict__ cs)            // [8192] fp32, pre-zeroed
{
  __shared__ __attribute__((aligned(16))) uint16_t XT[2][16384];  // 64KB stage
  __shared__ __attribute__((aligned(16))) uint16_t Ps[2][4096];   // 2x8KB dbuf

  const int tid  = threadIdx.x;
  const int w    = tid >> 6;
  const int lane = tid & 63;
  const int l31  = lane & 31;
  const int g    = lane >> 5;
  const int bid  = blockIdx.x;
  const int mt   = (bid & 1) | ((bid >> 3) << 1);   // 0..127
  const int q    = (bid >> 1) & 3;                  // n-split 0..3
  const int m0   = mt * 64;
  const int a_sub = w >> 1;                  // S n-sub (0/1)
  const int b_sub = w & 1;                   // S m-sub (0/1)

  const char* xafc = (const char*)xaf;
  const char* xbfc = (const char*)xbf;
  char*       XTc  = (char*)XT;
  char*       Psc  = (char*)Ps;

  // Xm B-fragments resident (64 VGPRs), one-time coalesced load
  bf16x8 Bm[16];
  {
    const char* bp = xafc + (size_t)(m0 / 32 + b_sub) * 16384 + g * 512 + l31 * 16;
    #pragma unroll
    for (int ks = 0; ks < 16; ++ks)
      Bm[ks] = __builtin_bit_cast(bf16x8, *(const int4v*)(bp + ks * 1024));
  }

  f32x16 accO[2][2];
  #pragma unroll
  for (int i = 0; i < 2; ++i)
    #pragma unroll
    for (int j = 0; j < 2; ++j)
      #pragma unroll
      for (int r = 0; r < 16; ++r) accO[i][j][r] = 0.0f;
  float csacc = 0.0f;

  const int mloc = 32 * b_sub + l31;
  const int l7   = l31 & 7;
  const int j0   = q * 32;                   // first n-tile index

  // prologue: stage tile j0 into XT[0] (identity copy, 8x 16B per thread)
  {
    const char* src = xafc + (size_t)j0 * 32768;
    #pragma unroll
    for (int r = 0; r < 8; ++r)
      dma16(src + tid * 16 + r * 4096, XTc + tid * 16 + r * 4096);
  }
  __syncthreads();   // one-time full drain; XT[0] ready

  bf16x8 Xf[2][4];   // PV A-frags for tile t (loaded in body t, used in t+1)

  for (int t = 0; t < 32; ++t) {
    const int jt  = j0 + t;
    const int cur = t & 1;
    char*       psW = Psc + cur * 8192;          // exp(t) target
    const char* psR = Psc + (cur ^ 1) * 8192;    // PV(t-1) source

    // ---- S(t) = Xn^T Xm : A-frags from XT[cur] (conflict-free b128) ----
    f32x16 s;
    #pragma unroll
    for (int r = 0; r < 16; ++r) s[r] = 0.0f;
    {
      const char* ap = XTc + cur * 32768 + a_sub * 16384 + g * 512 + l31 * 16;
      #pragma unroll
      for (int ks = 0; ks < 16; ++ks) {
        bf16x8 A = __builtin_bit_cast(bf16x8, *(const int4v*)(ap + ks * 1024));
        s = __builtin_amdgcn_mfma_f32_32x32x16_bf16(A, Bm[ks], s, 0, 0, 0);
      }
    }

    // ---- issue DMA(t+1) -> XT[cur^1] (its readers, S(t-1), are done:
    //      all waves passed bar(t-1)). Drained at bar(t) via vmcnt(8). ----
    if (t < 31) {
      const char* src = xafc + (size_t)(jt + 1) * 32768;
      #pragma unroll
      for (int r = 0; r < 8; ++r)
        dma16(src + tid * 16 + r * 4096,
              XTc + (cur ^ 1) * 32768 + tid * 16 + r * 4096);
    }
    // pin VMEM order (DMA before Xf) but let MFMA/VALU/DS cross freely
    __builtin_amdgcn_sched_barrier(0x38F);

    // ---- PV(t-1): O += Xn(t-1) * P(t-1)  (Ps[cur^1], Xf regs) ----
    if (t > 0) {
      #pragma unroll
      for (int ks = 0; ks < 4; ++ks) {
        bf16x8 Bp[2];
        #pragma unroll
        for (int mm = 0; mm < 2; ++mm) {
          int mrow = 32 * mm + l31;
          int p = (2 * ks + g) ^ l7;
          Bp[mm] = __builtin_bit_cast(bf16x8,
              *(const int4v*)(psR + mrow * 128 + p * 16));
        }
        #pragma unroll
        for (int t2 = 0; t2 < 2; ++t2) {
          accO[t2][0] = __builtin_amdgcn_mfma_f32_32x32x16_bf16(Xf[t2][ks], Bp[0], accO[t2][0], 0,0,0);
          accO[t2][1] = __builtin_amdgcn_mfma_f32_32x32x16_bf16(Xf[t2][ks], Bp[1], accO[t2][1], 0,0,0);
        }
      }
    }

    // ---- issue Xf(t) (PV A-frags for body t+1); flies across exp+bar+S ----
    {
      const int n0 = jt * 64;
      #pragma unroll
      for (int t2 = 0; t2 < 2; ++t2) {
        const char* xp = xbfc + (size_t)(2 * w + t2) * 524288 +
                         (size_t)(n0 >> 3) * 512 + g * 512 + l31 * 16;
        #pragma unroll
        for (int ks = 0; ks < 4; ++ks)
          Xf[t2][ks] = __builtin_bit_cast(bf16x8, *(const int4v*)(xp + ks * 1024));
      }
    }

    // ---- exp(t) -> Ps[cur] (cvt_pk RNE packing; co-issues with PV MFMA) ----
    #pragma unroll
    for (int k = 0; k < 4; ++k) {
      float e0 = __expf(6.0f * s[4*k+0]);
      float e1 = __expf(6.0f * s[4*k+1]);
      float e2 = __expf(6.0f * s[4*k+2]);
      float e3 = __expf(6.0f * s[4*k+3]);
      csacc += (e0 + e1) + (e2 + e3);
      uint32_t lo, hi;
      asm("v_cvt_pk_bf16_f32 %0, %1, %2" : "=v"(lo) : "v"(e0), "v"(e1));
      asm("v_cvt_pk_bf16_f32 %0, %1, %2" : "=v"(hi) : "v"(e2), "v"(e3));
      int p = (4 * a_sub + k) ^ (mloc & 7);
      *(uint64_t*)(psW + mloc * 128 + p * 16 + 8 * g) =
          ((uint64_t)hi << 32) | lo;
    }

    // ---- bar(t): Ps[cur] visible; DMA(t+1) (oldest 8) done; Xf(t) flies ----
    asm volatile("s_waitcnt vmcnt(8) lgkmcnt(0)" ::: "memory");
    __builtin_amdgcn_s_barrier();
  }

  // ---- final PV(31): Ps buffer written by body 31 (cur=1) ----
  {
    const char* psR = Psc + 8192;
    #pragma unroll
    for (int ks = 0; ks < 4; ++ks) {
      bf16x8 Bp[2];
      #pragma unroll
      for (int mm = 0; mm < 2; ++mm) {
        int mrow = 32 * mm + l31;
        int p = (2 * ks + g) ^ l7;
        Bp[mm] = __builtin_bit_cast(bf16x8,
            *(const int4v*)(psR + mrow * 128 + p * 16));
      }
      #pragma unroll
      for (int t2 = 0; t2 < 2; ++t2) {
        accO[t2][0] = __builtin_amdgcn_mfma_f32_32x32x16_bf16(Xf[t2][ks], Bp[0], accO[t2][0], 0,0,0);
        accO[t2][1] = __builtin_amdgcn_mfma_f32_32x32x16_bf16(Xf[t2][ks], Bp[1], accO[t2][1], 0,0,0);
      }
    }
  }

  // ---- epilogue: merge partials ----
  csacc += __shfl_xor(csacc, 32, 64);
  if (g == 0) atomicAdd(&cs[m0 + mloc], csacc);
  #pragma unroll
  for (int t2 = 0; t2 < 2; ++t2)
    #pragma unroll
    for (int mm = 0; mm < 2; ++mm)
      #pragma unroll
      for (int r = 0; r < 16; ++r) {
        int drow = 32 * (2 * w + t2) + (r & 3) + 8 * (r >> 2) + 4 * g;
        int mg   = m0 + 32 * mm + l31;
        atomicAdd(&num[(size_t)drow * NPTS + mg], accO[t2][mm][r]);
      }
}

// ---------------------------------------------------------------------------
// Combine. mode1: v = num/cs -> yout; zero num after read; zero cs_next.
//          mode0: v = src (initial fp32 X). Both: emit xaf + xbf frags.
// float4-vectorized global traffic.
// ---------------------------------------------------------------------------
__global__ __launch_bounds__(256) void ms_combine(
    const float* __restrict__ src, const float* __restrict__ csr,
    float* __restrict__ csz, float* __restrict__ yout,
    float* __restrict__ numz,
    uint16_t* __restrict__ xaf, uint16_t* __restrict__ xbf,
    const int mode)
{
  __shared__ uint16_t T[64][66];
  const int tid = threadIdx.x;
  const int n0 = blockIdx.x * 64;
  const int d0 = blockIdx.y * 64;

  #pragma unroll
  for (int i = 0; i < 4; ++i) {
    int e  = tid + i * 256;              // float4 slot
    int dl = e >> 4, nq = e & 15;
    size_t idx = (size_t)(d0 + dl) * NPTS + (n0 + nq * 4);
    f32x4 v = *(const f32x4*)(src + idx);
    if (mode) {
      f32x4 c = *(const f32x4*)(csr + n0 + nq * 4);
      v /= c;
      *(f32x4*)(yout + idx) = v;
      f32x4 z = {0.f, 0.f, 0.f, 0.f};
      *(f32x4*)(numz + idx) = z;
    }
    #pragma unroll
    for (int k = 0; k < 4; ++k) T[dl][nq * 4 + k] = f2bf(v[k]);
  }
  if (mode && blockIdx.y == 0 && tid < 64) csz[n0 + tid] = 0.0f;
  __syncthreads();

  char* xafc = (char*)xaf;
  char* xbfc = (char*)xbf;
  // xaf chunks: (nb, s, lane) -> T[s*8 + j][nb*32+lane]
  #pragma unroll
  for (int i = 0; i < 2; ++i) {
    int c  = tid + i * 256;
    int nb = c >> 8, s2 = (c >> 5) & 7, ln = c & 31;
    union { uint32_t u[4]; int4v v; } pk;
    #pragma unroll
    for (int k = 0; k < 4; ++k) {
      uint32_t lo = T[s2 * 8 + 2 * k][nb * 32 + ln];
      uint32_t hi = T[s2 * 8 + 2 * k + 1][nb * 32 + ln];
      pk.u[k] = lo | (hi << 16);
    }
    *(int4v*)(xafc + (size_t)(n0 / 32 + nb) * 16384 +
              (size_t)(d0 / 8 + s2) * 512 + ln * 16) = pk.v;
  }
  // xbf chunks: (db, u, lane) -> T[db*32+lane][u*8 + j]  (row-contiguous)
  #pragma unroll
  for (int i = 0; i < 2; ++i) {
    int c  = tid + i * 256;
    int db = c >> 8, uu = (c >> 5) & 7, ln = c & 31;
    const uint16_t* tr = &T[db * 32 + ln][uu * 8];
    union { uint32_t u[4]; int4v v; } pk;
    #pragma unroll
    for (int k = 0; k < 4; ++k)
      pk.u[k] = (uint32_t)tr[2 * k] | ((uint32_t)tr[2 * k + 1] << 16);
    *(int4v*)(xbfc + (size_t)(d0 / 32 + db) * 524288 +
              (size_t)(n0 / 8 + uu) * 512 + ln * 16) = pk.v;
  }
}

extern "C" void kernel_launch(void* const* d_in, const int* in_sizes, int n_in,
                              void* d_out, int out_size, void* d_ws, size_t ws_size,
                              hipStream_t stream)
{
  (void)in_sizes; (void)n_in; (void)out_size; (void)ws_size;
  const float* X = (const float*)d_in[0];
  float* out = (float*)d_out;
  char* ws = (char*)d_ws;
  // ws: [0,4M) xaf ; [4M,8M) xbf ; [8M,16M) num ; [16M,+32K) cs0 ; [+32K) cs1
  uint16_t* xaf = (uint16_t*)(ws);
  uint16_t* xbf = (uint16_t*)(ws + (4u << 20));
  float*    num = (float*)   (ws + (8u << 20));
  float*    cs0 = (float*)   (ws + (16u << 20));
  float*    cs1 = (float*)   (ws + (16u << 20) + 32768);

  // zero num + both cs buffers once per call (ws is re-poisoned each call)
  hipMemsetAsync(ws + (8u << 20), 0, (8u << 20) + 65536, stream);

  dim3 cgrid(NPTS / 64, DFEAT / 64);
  ms_combine<<<cgrid, 256, 0, stream>>>(X, nullptr, nullptr, nullptr, nullptr,
                                        xaf, xbf, 0);
  for (int it = 0; it < 3; ++it) {
    float* csA = (it & 1) ? cs1 : cs0;
    float* csB = (it & 1) ? cs0 : cs1;
    ms_fused<<<512, 256, 0, stream>>>(xaf, xbf, num, csA);
    ms_combine<<<cgrid, 256, 0, stream>>>(num, csA, csB,
                                          out + (size_t)it * DFEAT * NPTS,
                                          num, xaf, xbf, 1);
  }
}

// Round 7
// 337.547 us; speedup vs baseline: 1.0678x; 1.0016x over previous
//
#include <hip/hip_runtime.h>
#include <hip/hip_bf16.h>
#include <stdint.h>

#define DFEAT 256
#define NPTS  8192

typedef __attribute__((ext_vector_type(8)))  short bf16x8;   // 8 bf16 = 4 VGPRs
typedef __attribute__((ext_vector_type(16))) float f32x16;   // 32x32 C/D
typedef __attribute__((ext_vector_type(4)))  int   int4v;
typedef __attribute__((ext_vector_type(4)))  float f32x4;

#define AS1 __attribute__((address_space(1)))
#define AS3 __attribute__((address_space(3)))

__device__ inline void dma16(const void* g, void* l) {
  // async global->LDS, 16B/lane; LDS dest = wave-uniform base + lane*16
  __builtin_amdgcn_global_load_lds((const AS1 uint32_t*)g, (AS3 uint32_t*)l, 16, 0, 0);
}

__device__ inline uint16_t f2bf(float f) {  // RNE fp32->bf16
  union { float f; uint32_t u; } v; v.f = f;
  return (uint16_t)((v.u + 0x7FFFu + ((v.u >> 16) & 1u)) >> 16);
}

// ---------------------------------------------------------------------------
// ws fragment layouts (written by ms_combine):
//  xaf: per 32-point block nb, chunk s=2*ks+g, lane 0..31:
//       X[d = s*8 .. +8][pt = nb*32+lane]  (A/B-frag order, k=d)
//       byte addr = nb*16384 + s*512 + lane*16.     (4 MB)
//  xbf: per 32-d block db, chunk u (n/8), lane:
//       X[d = db*32+lane][n = u*8 .. +8]   (PV A-frag order, k=n)
//       byte addr = db*524288 + u*512 + lane*16.    (4 MB)
// ---------------------------------------------------------------------------

// R7: R6's single-barrier pipelined body (the only structure that won:
// 94.6 -> 89.7us), with BOTH VMEM streams issued at the TOP of the body:
//   [issue DMA(t+1) -> XT[cur^1]; issue Xf(t) -> ping-pong reg buf]
//   S(t) from XT[cur]   (LDS only; VMEM flies across it)
//   PV(t-1) from Ps[cur^1] + Xf(t-1)   (compiler auto vmcnt(16): keeps
//                                        DMA(t+1)+Xf(t) in flight)
//   exp(t) -> Ps[cur]
//   s_waitcnt vmcnt(8) lgkmcnt(0); s_barrier   (DMA done; Xf(t) flies)
// DMA flight window grows by the whole S phase; Xf by a full body.
// Xf ping-pong (XfE/XfO) is statically indexed via body-pair unroll
// (+32 VGPR, ~212 total, still 2 waves/SIMD). XT[cur^1] is free at body
// start: its reader S(t-1) drained at bar(t-1). No vmcnt(0) in the loop.
// Kept: Ps dbuf, cvt_pk packing, XCD-pair blockIdx swizzle.
__global__ __launch_bounds__(256, 2) void ms_fused(
    const uint16_t* __restrict__ xaf,
    const uint16_t* __restrict__ xbf,
    float* __restrict__ num,           // [256][8192] fp32, pre-zeroed
    float* __restrict__ cs)            // [8192] fp32, pre-zeroed
{
  __shared__ __attribute__((aligned(16))) uint16_t XT[2][16384];  // 64KB stage
  __shared__ __attribute__((aligned(16))) uint16_t Ps[2][4096];   // 2x8KB dbuf

  const int tid  = threadIdx.x;
  const int w    = tid >> 6;
  const int lane = tid & 63;
  const int l31  = lane & 31;
  const int g    = lane >> 5;
  const int bid  = blockIdx.x;
  const int mt   = (bid & 1) | ((bid >> 3) << 1);   // 0..127
  const int q    = (bid >> 1) & 3;                  // n-split 0..3
  const int m0   = mt * 64;
  const int a_sub = w >> 1;                  // S n-sub (0/1)
  const int b_sub = w & 1;                   // S m-sub (0/1)

  const char* xafc = (const char*)xaf;
  const char* xbfc = (const char*)xbf;
  char*       XTc  = (char*)XT;
  char*       Psc  = (char*)Ps;

  // Xm B-fragments resident (64 VGPRs), one-time coalesced load
  bf16x8 Bm[16];
  {
    const char* bp = xafc + (size_t)(m0 / 32 + b_sub) * 16384 + g * 512 + l31 * 16;
    #pragma unroll
    for (int ks = 0; ks < 16; ++ks)
      Bm[ks] = __builtin_bit_cast(bf16x8, *(const int4v*)(bp + ks * 1024));
  }

  f32x16 accO[2][2];
  #pragma unroll
  for (int i = 0; i < 2; ++i)
    #pragma unroll
    for (int j = 0; j < 2; ++j)
      #pragma unroll
      for (int r = 0; r < 16; ++r) accO[i][j][r] = 0.0f;
  float csacc = 0.0f;

  const int mloc = 32 * b_sub + l31;
  const int l7   = l31 & 7;
  const int j0   = q * 32;                   // first n-tile index

  // prologue: stage tile j0 into XT[0] (identity copy, 8x 16B per thread)
  {
    const char* src = xafc + (size_t)j0 * 32768;
    #pragma unroll
    for (int r = 0; r < 8; ++r)
      dma16(src + tid * 16 + r * 4096, XTc + tid * 16 + r * 4096);
  }
  __syncthreads();   // one-time full drain; XT[0] ready

  bf16x8 XfE[2][4], XfO[2][4];   // ping-pong PV A-frag buffers

// body T_: cur=CUR_ (=T_&1), loads Xf(T_) into XF_LD, PV(T_-1) uses XF_USE
#define MS_BODY(T_, CUR_, XF_LD, XF_USE, DO_PV)                               \
  {                                                                           \
    const int jt_ = j0 + (T_);                                                \
    char*       psW_ = Psc + (CUR_) * 8192;                                   \
    const char* psR_ = Psc + ((CUR_) ^ 1) * 8192;                             \
    /* issue DMA(t+1) -> XT[cur^1] (freed at bar(t-1)) */                     \
    if ((T_) < 31) {                                                          \
      const char* src_ = xafc + (size_t)(jt_ + 1) * 32768;                    \
      _Pragma("unroll")                                                       \
      for (int r = 0; r < 8; ++r)                                             \
        dma16(src_ + tid * 16 + r * 4096,                                     \
              XTc + ((CUR_) ^ 1) * 32768 + tid * 16 + r * 4096);              \
    }                                                                         \
    /* issue Xf(t) (consumed by PV in body t+1) */                            \
    {                                                                         \
      const int n0_ = jt_ * 64;                                               \
      _Pragma("unroll")                                                       \
      for (int t2 = 0; t2 < 2; ++t2) {                                        \
        const char* xp_ = xbfc + (size_t)(2 * w + t2) * 524288 +              \
                          (size_t)(n0_ >> 3) * 512 + g * 512 + l31 * 16;      \
        _Pragma("unroll")                                                     \
        for (int ks = 0; ks < 4; ++ks)                                        \
          XF_LD[t2][ks] =                                                     \
              __builtin_bit_cast(bf16x8, *(const int4v*)(xp_ + ks * 1024));   \
      }                                                                       \
    }                                                                         \
    /* VMEM pinned above this point; ALU/MFMA/DS may cross freely */          \
    __builtin_amdgcn_sched_barrier(0x38F);                                    \
    /* ---- S(t) = Xn^T Xm from XT[cur] (conflict-free b128) ---- */          \
    f32x16 s;                                                                 \
    _Pragma("unroll")                                                         \
    for (int r = 0; r < 16; ++r) s[r] = 0.0f;                                 \
    {                                                                         \
      const char* ap_ = XTc + (CUR_) * 32768 + a_sub * 16384 + g * 512 +      \
                        l31 * 16;                                             \
      _Pragma("unroll")                                                       \
      for (int ks = 0; ks < 16; ++ks) {                                       \
        bf16x8 A = __builtin_bit_cast(bf16x8,                                 \
                                      *(const int4v*)(ap_ + ks * 1024));      \
        s = __builtin_amdgcn_mfma_f32_32x32x16_bf16(A, Bm[ks], s, 0, 0, 0);   \
      }                                                                       \
    }                                                                         \
    /* ---- PV(t-1): O += Xn(t-1) * P(t-1) ---- */                            \
    if (DO_PV) {                                                              \
      _Pragma("unroll")                                                       \
      for (int ks = 0; ks < 4; ++ks) {                                        \
        bf16x8 Bp[2];                                                         \
        _Pragma("unroll")                                                     \
        for (int mm = 0; mm < 2; ++mm) {                                      \
          int mrow = 32 * mm + l31;                                           \
          int p = (2 * ks + g) ^ l7;                                          \
          Bp[mm] = __builtin_bit_cast(bf16x8,                                 \
              *(const int4v*)(psR_ + mrow * 128 + p * 16));                   \
        }                                                                     \
        _Pragma("unroll")                                                     \
        for (int t2 = 0; t2 < 2; ++t2) {                                      \
          accO[t2][0] = __builtin_amdgcn_mfma_f32_32x32x16_bf16(              \
              XF_USE[t2][ks], Bp[0], accO[t2][0], 0, 0, 0);                   \
          accO[t2][1] = __builtin_amdgcn_mfma_f32_32x32x16_bf16(              \
              XF_USE[t2][ks], Bp[1], accO[t2][1], 0, 0, 0);                   \
        }                                                                     \
      }                                                                       \
    }                                                                         \
    /* ---- exp(t) -> Ps[cur] (cvt_pk RNE packing) ---- */                    \
    _Pragma("unroll")                                                         \
    for (int k = 0; k < 4; ++k) {                                             \
      float e0 = __expf(6.0f * s[4 * k + 0]);                                 \
      float e1 = __expf(6.0f * s[4 * k + 1]);                                 \
      float e2 = __expf(6.0f * s[4 * k + 2]);                                 \
      float e3 = __expf(6.0f * s[4 * k + 3]);                                 \
      csacc += (e0 + e1) + (e2 + e3);                                         \
      uint32_t lo, hi;                                                        \
      asm("v_cvt_pk_bf16_f32 %0, %1, %2" : "=v"(lo) : "v"(e0), "v"(e1));      \
      asm("v_cvt_pk_bf16_f32 %0, %1, %2" : "=v"(hi) : "v"(e2), "v"(e3));      \
      int p = (4 * a_sub + k) ^ (mloc & 7);                                   \
      *(uint64_t*)(psW_ + mloc * 128 + p * 16 + 8 * g) =                      \
          ((uint64_t)hi << 32) | lo;                                          \
    }                                                                         \
    /* bar(t): Ps[cur] visible; DMA(t+1) (oldest 8) done; Xf(t) flies */      \
    asm volatile("s_waitcnt vmcnt(8) lgkmcnt(0)" ::: "memory");               \
    __builtin_amdgcn_s_barrier();                                             \
  }

  MS_BODY(0, 0, XfE, XfO, false)
  for (int tp = 0; tp < 15; ++tp) {
    const int tb = 2 * tp;
    MS_BODY(tb + 1, 1, XfO, XfE, true)
    MS_BODY(tb + 2, 0, XfE, XfO, true)
  }
  MS_BODY(31, 1, XfO, XfE, true)
#undef MS_BODY

  // ---- final PV(31): P from Ps[1] (written by body 31), Xf(31)=XfO ----
  {
    const char* psR = Psc + 8192;
    #pragma unroll
    for (int ks = 0; ks < 4; ++ks) {
      bf16x8 Bp[2];
      #pragma unroll
      for (int mm = 0; mm < 2; ++mm) {
        int mrow = 32 * mm + l31;
        int p = (2 * ks + g) ^ l7;
        Bp[mm] = __builtin_bit_cast(bf16x8,
            *(const int4v*)(psR + mrow * 128 + p * 16));
      }
      #pragma unroll
      for (int t2 = 0; t2 < 2; ++t2) {
        accO[t2][0] = __builtin_amdgcn_mfma_f32_32x32x16_bf16(XfO[t2][ks], Bp[0], accO[t2][0], 0,0,0);
        accO[t2][1] = __builtin_amdgcn_mfma_f32_32x32x16_bf16(XfO[t2][ks], Bp[1], accO[t2][1], 0,0,0);
      }
    }
  }

  // ---- epilogue: merge partials ----
  csacc += __shfl_xor(csacc, 32, 64);
  if (g == 0) atomicAdd(&cs[m0 + mloc], csacc);
  #pragma unroll
  for (int t2 = 0; t2 < 2; ++t2)
    #pragma unroll
    for (int mm = 0; mm < 2; ++mm)
      #pragma unroll
      for (int r = 0; r < 16; ++r) {
        int drow = 32 * (2 * w + t2) + (r & 3) + 8 * (r >> 2) + 4 * g;
        int mg   = m0 + 32 * mm + l31;
        atomicAdd(&num[(size_t)drow * NPTS + mg], accO[t2][mm][r]);
      }
}

// ---------------------------------------------------------------------------
// Combine. mode1: v = num/cs -> yout; zero num after read; zero cs_next.
//          mode0: v = src (initial fp32 X). Both: emit xaf + xbf frags.
// float4-vectorized global traffic.
// ---------------------------------------------------------------------------
__global__ __launch_bounds__(256) void ms_combine(
    const float* __restrict__ src, const float* __restrict__ csr,
    float* __restrict__ csz, float* __restrict__ yout,
    float* __restrict__ numz,
    uint16_t* __restrict__ xaf, uint16_t* __restrict__ xbf,
    const int mode)
{
  __shared__ uint16_t T[64][66];
  const int tid = threadIdx.x;
  const int n0 = blockIdx.x * 64;
  const int d0 = blockIdx.y * 64;

  #pragma unroll
  for (int i = 0; i < 4; ++i) {
    int e  = tid + i * 256;              // float4 slot
    int dl = e >> 4, nq = e & 15;
    size_t idx = (size_t)(d0 + dl) * NPTS + (n0 + nq * 4);
    f32x4 v = *(const f32x4*)(src + idx);
    if (mode) {
      f32x4 c = *(const f32x4*)(csr + n0 + nq * 4);
      v /= c;
      *(f32x4*)(yout + idx) = v;
      f32x4 z = {0.f, 0.f, 0.f, 0.f};
      *(f32x4*)(numz + idx) = z;
    }
    #pragma unroll
    for (int k = 0; k < 4; ++k) T[dl][nq * 4 + k] = f2bf(v[k]);
  }
  if (mode && blockIdx.y == 0 && tid < 64) csz[n0 + tid] = 0.0f;
  __syncthreads();

  char* xafc = (char*)xaf;
  char* xbfc = (char*)xbf;
  // xaf chunks: (nb, s, lane) -> T[s*8 + j][nb*32+lane]
  #pragma unroll
  for (int i = 0; i < 2; ++i) {
    int c  = tid + i * 256;
    int nb = c >> 8, s2 = (c >> 5) & 7, ln = c & 31;
    union { uint32_t u[4]; int4v v; } pk;
    #pragma unroll
    for (int k = 0; k < 4; ++k) {
      uint32_t lo = T[s2 * 8 + 2 * k][nb * 32 + ln];
      uint32_t hi = T[s2 * 8 + 2 * k + 1][nb * 32 + ln];
      pk.u[k] = lo | (hi << 16);
    }
    *(int4v*)(xafc + (size_t)(n0 / 32 + nb) * 16384 +
              (size_t)(d0 / 8 + s2) * 512 + ln * 16) = pk.v;
  }
  // xbf chunks: (db, u, lane) -> T[db*32+lane][u*8 + j]  (row-contiguous)
  #pragma unroll
  for (int i = 0; i < 2; ++i) {
    int c  = tid + i * 256;
    int db = c >> 8, uu = (c >> 5) & 7, ln = c & 31;
    const uint16_t* tr = &T[db * 32 + ln][uu * 8];
    union { uint32_t u[4]; int4v v; } pk;
    #pragma unroll
    for (int k = 0; k < 4; ++k)
      pk.u[k] = (uint32_t)tr[2 * k] | ((uint32_t)tr[2 * k + 1] << 16);
    *(int4v*)(xbfc + (size_t)(d0 / 32 + db) * 524288 +
              (size_t)(n0 / 8 + uu) * 512 + ln * 16) = pk.v;
  }
}

extern "C" void kernel_launch(void* const* d_in, const int* in_sizes, int n_in,
                              void* d_out, int out_size, void* d_ws, size_t ws_size,
                              hipStream_t stream)
{
  (void)in_sizes; (void)n_in; (void)out_size; (void)ws_size;
  const float* X = (const float*)d_in[0];
  float* out = (float*)d_out;
  char* ws = (char*)d_ws;
  // ws: [0,4M) xaf ; [4M,8M) xbf ; [8M,16M) num ; [16M,+32K) cs0 ; [+32K) cs1
  uint16_t* xaf = (uint16_t*)(ws);
  uint16_t* xbf = (uint16_t*)(ws + (4u << 20));
  float*    num = (float*)   (ws + (8u << 20));
  float*    cs0 = (float*)   (ws + (16u << 20));
  float*    cs1 = (float*)   (ws + (16u << 20) + 32768);

  // zero num + both cs buffers once per call (ws is re-poisoned each call)
  hipMemsetAsync(ws + (8u << 20), 0, (8u << 20) + 65536, stream);

  dim3 cgrid(NPTS / 64, DFEAT / 64);
  ms_combine<<<cgrid, 256, 0, stream>>>(X, nullptr, nullptr, nullptr, nullptr,
                                        xaf, xbf, 0);
  for (int it = 0; it < 3; ++it) {
    float* csA = (it & 1) ? cs1 : cs0;
    float* csB = (it & 1) ? cs0 : cs1;
    ms_fused<<<512, 256, 0, stream>>>(xaf, xbf, num, csA);
    ms_combine<<<cgrid, 256, 0, stream>>>(num, csA, csB,
                                          out + (size_t)it * DFEAT * NPTS,
                                          num, xaf, xbf, 1);
  }
}

// Round 8
// 303.250 us; speedup vs baseline: 1.1886x; 1.1131x over previous
//
#include <hip/hip_runtime.h>
#include <hip/hip_bf16.h>
#include <stdint.h>

#define DFEAT 256
#define NPTS  8192

typedef __attribute__((ext_vector_type(8)))  short bf16x8;   // 8 bf16 = 4 VGPRs
typedef __attribute__((ext_vector_type(16))) float f32x16;   // 32x32 C/D
typedef __attribute__((ext_vector_type(4)))  int   int4v;
typedef __attribute__((ext_vector_type(4)))  float f32x4;

#define AS1 __attribute__((address_space(1)))
#define AS3 __attribute__((address_space(3)))

__device__ inline void dma16(const void* g, void* l) {
  // async global->LDS, 16B/lane; LDS dest = wave-uniform base + lane*16
  __builtin_amdgcn_global_load_lds((const AS1 uint32_t*)g, (AS3 uint32_t*)l, 16, 0, 0);
}

__device__ inline uint16_t f2bf(float f) {  // RNE fp32->bf16
  union { float f; uint32_t u; } v; v.f = f;
  return (uint16_t)((v.u + 0x7FFFu + ((v.u >> 16) & 1u)) >> 16);
}

// ---------------------------------------------------------------------------
// ws fragment layouts (written by ms_combine):
//  xaf: per 32-point block nb, chunk s=2*ks+g, lane 0..31:
//       X[d = s*8 .. +8][pt = nb*32+lane]  (A/B-frag order, k=d)
//       byte addr = nb*16384 + s*512 + lane*16.     (4 MB)
//  xbf: per 32-d block db, chunk u (n/8), lane:
//       X[d = db*32+lane][n = u*8 .. +8]   (PV A-frag order, k=n)
//       byte addr = db*524288 + u*512 + lane*16.    (4 MB)
// R8 partials (ws is 256MB; poison pass showed 262144KB):
//  num_p[4][256][8192] f32 (32MB): q-split q writes slab q with PLAIN stores
//       (single writer per element). No atomics, no zeroing.
//  cs_p[8][8192] f32 (256KB): slice 2q+a_sub, plain stores, single writer.
// ---------------------------------------------------------------------------

// R8: fused K-loop identical to R7 (single-barrier, dual top-of-body VMEM
// prefetch). Epilogue: atomicAdd -> plain stores into private q-slab.
// R7 counters showed WRITE_SIZE=33MB (4 q-writers RMW-dirtying the 8MB num
// 4x) -- the atomic epilogue was ~6-8us/dispatch of HBM + RMW traffic.
__global__ __launch_bounds__(256, 2) void ms_fused(
    const uint16_t* __restrict__ xaf,
    const uint16_t* __restrict__ xbf,
    float* __restrict__ nump,          // [4][256][8192] fp32 partial slabs
    float* __restrict__ csp)           // [8][8192] fp32 partial slices
{
  __shared__ __attribute__((aligned(16))) uint16_t XT[2][16384];  // 64KB stage
  __shared__ __attribute__((aligned(16))) uint16_t Ps[2][4096];   // 2x8KB dbuf

  const int tid  = threadIdx.x;
  const int w    = tid >> 6;
  const int lane = tid & 63;
  const int l31  = lane & 31;
  const int g    = lane >> 5;
  const int bid  = blockIdx.x;
  const int mt   = (bid & 1) | ((bid >> 3) << 1);   // 0..127
  const int q    = (bid >> 1) & 3;                  // n-split 0..3
  const int m0   = mt * 64;
  const int a_sub = w >> 1;                  // S n-sub (0/1)
  const int b_sub = w & 1;                   // S m-sub (0/1)

  const char* xafc = (const char*)xaf;
  const char* xbfc = (const char*)xbf;
  char*       XTc  = (char*)XT;
  char*       Psc  = (char*)Ps;

  // Xm B-fragments resident (64 VGPRs), one-time coalesced load
  bf16x8 Bm[16];
  {
    const char* bp = xafc + (size_t)(m0 / 32 + b_sub) * 16384 + g * 512 + l31 * 16;
    #pragma unroll
    for (int ks = 0; ks < 16; ++ks)
      Bm[ks] = __builtin_bit_cast(bf16x8, *(const int4v*)(bp + ks * 1024));
  }

  f32x16 accO[2][2];
  #pragma unroll
  for (int i = 0; i < 2; ++i)
    #pragma unroll
    for (int j = 0; j < 2; ++j)
      #pragma unroll
      for (int r = 0; r < 16; ++r) accO[i][j][r] = 0.0f;
  float csacc = 0.0f;

  const int mloc = 32 * b_sub + l31;
  const int l7   = l31 & 7;
  const int j0   = q * 32;                   // first n-tile index

  // prologue: stage tile j0 into XT[0] (identity copy, 8x 16B per thread)
  {
    const char* src = xafc + (size_t)j0 * 32768;
    #pragma unroll
    for (int r = 0; r < 8; ++r)
      dma16(src + tid * 16 + r * 4096, XTc + tid * 16 + r * 4096);
  }
  __syncthreads();   // one-time full drain; XT[0] ready

  bf16x8 XfE[2][4], XfO[2][4];   // ping-pong PV A-frag buffers

// body T_: cur=CUR_ (=T_&1), loads Xf(T_) into XF_LD, PV(T_-1) uses XF_USE
#define MS_BODY(T_, CUR_, XF_LD, XF_USE, DO_PV)                               \
  {                                                                           \
    const int jt_ = j0 + (T_);                                                \
    char*       psW_ = Psc + (CUR_) * 8192;                                   \
    const char* psR_ = Psc + ((CUR_) ^ 1) * 8192;                             \
    /* issue DMA(t+1) -> XT[cur^1] (freed at bar(t-1)) */                     \
    if ((T_) < 31) {                                                          \
      const char* src_ = xafc + (size_t)(jt_ + 1) * 32768;                    \
      _Pragma("unroll")                                                       \
      for (int r = 0; r < 8; ++r)                                             \
        dma16(src_ + tid * 16 + r * 4096,                                     \
              XTc + ((CUR_) ^ 1) * 32768 + tid * 16 + r * 4096);              \
    }                                                                         \
    /* issue Xf(t) (consumed by PV in body t+1) */                            \
    {                                                                         \
      const int n0_ = jt_ * 64;                                               \
      _Pragma("unroll")                                                       \
      for (int t2 = 0; t2 < 2; ++t2) {                                        \
        const char* xp_ = xbfc + (size_t)(2 * w + t2) * 524288 +              \
                          (size_t)(n0_ >> 3) * 512 + g * 512 + l31 * 16;      \
        _Pragma("unroll")                                                     \
        for (int ks = 0; ks < 4; ++ks)                                        \
          XF_LD[t2][ks] =                                                     \
              __builtin_bit_cast(bf16x8, *(const int4v*)(xp_ + ks * 1024));   \
      }                                                                       \
    }                                                                         \
    /* VMEM pinned above this point; ALU/MFMA/DS may cross freely */          \
    __builtin_amdgcn_sched_barrier(0x38F);                                    \
    /* ---- S(t) = Xn^T Xm from XT[cur] (conflict-free b128) ---- */          \
    f32x16 s;                                                                 \
    _Pragma("unroll")                                                         \
    for (int r = 0; r < 16; ++r) s[r] = 0.0f;                                 \
    {                                                                         \
      const char* ap_ = XTc + (CUR_) * 32768 + a_sub * 16384 + g * 512 +      \
                        l31 * 16;                                             \
      _Pragma("unroll")                                                       \
      for (int ks = 0; ks < 16; ++ks) {                                       \
        bf16x8 A = __builtin_bit_cast(bf16x8,                                 \
                                      *(const int4v*)(ap_ + ks * 1024));      \
        s = __builtin_amdgcn_mfma_f32_32x32x16_bf16(A, Bm[ks], s, 0, 0, 0);   \
      }                                                                       \
    }                                                                         \
    /* ---- PV(t-1): O += Xn(t-1) * P(t-1) ---- */                            \
    if (DO_PV) {                                                              \
      _Pragma("unroll")                                                       \
      for (int ks = 0; ks < 4; ++ks) {                                        \
        bf16x8 Bp[2];                                                         \
        _Pragma("unroll")                                                     \
        for (int mm = 0; mm < 2; ++mm) {                                      \
          int mrow = 32 * mm + l31;                                           \
          int p = (2 * ks + g) ^ l7;                                          \
          Bp[mm] = __builtin_bit_cast(bf16x8,                                 \
              *(const int4v*)(psR_ + mrow * 128 + p * 16));                   \
        }                                                                     \
        _Pragma("unroll")                                                     \
        for (int t2 = 0; t2 < 2; ++t2) {                                      \
          accO[t2][0] = __builtin_amdgcn_mfma_f32_32x32x16_bf16(              \
              XF_USE[t2][ks], Bp[0], accO[t2][0], 0, 0, 0);                   \
          accO[t2][1] = __builtin_amdgcn_mfma_f32_32x32x16_bf16(              \
              XF_USE[t2][ks], Bp[1], accO[t2][1], 0, 0, 0);                   \
        }                                                                     \
      }                                                                       \
    }                                                                         \
    /* ---- exp(t) -> Ps[cur] (cvt_pk RNE packing) ---- */                    \
    _Pragma("unroll")                                                         \
    for (int k = 0; k < 4; ++k) {                                             \
      float e0 = __expf(6.0f * s[4 * k + 0]);                                 \
      float e1 = __expf(6.0f * s[4 * k + 1]);                                 \
      float e2 = __expf(6.0f * s[4 * k + 2]);                                 \
      float e3 = __expf(6.0f * s[4 * k + 3]);                                 \
      csacc += (e0 + e1) + (e2 + e3);                                         \
      uint32_t lo, hi;                                                        \
      asm("v_cvt_pk_bf16_f32 %0, %1, %2" : "=v"(lo) : "v"(e0), "v"(e1));      \
      asm("v_cvt_pk_bf16_f32 %0, %1, %2" : "=v"(hi) : "v"(e2), "v"(e3));      \
      int p = (4 * a_sub + k) ^ (mloc & 7);                                   \
      *(uint64_t*)(psW_ + mloc * 128 + p * 16 + 8 * g) =                      \
          ((uint64_t)hi << 32) | lo;                                          \
    }                                                                         \
    /* bar(t): Ps[cur] visible; DMA(t+1) (oldest 8) done; Xf(t) flies */      \
    asm volatile("s_waitcnt vmcnt(8) lgkmcnt(0)" ::: "memory");               \
    __builtin_amdgcn_s_barrier();                                             \
  }

  MS_BODY(0, 0, XfE, XfO, false)
  for (int tp = 0; tp < 15; ++tp) {
    const int tb = 2 * tp;
    MS_BODY(tb + 1, 1, XfO, XfE, true)
    MS_BODY(tb + 2, 0, XfE, XfO, true)
  }
  MS_BODY(31, 1, XfO, XfE, true)
#undef MS_BODY

  // ---- final PV(31): P from Ps[1] (written by body 31), Xf(31)=XfO ----
  {
    const char* psR = Psc + 8192;
    #pragma unroll
    for (int ks = 0; ks < 4; ++ks) {
      bf16x8 Bp[2];
      #pragma unroll
      for (int mm = 0; mm < 2; ++mm) {
        int mrow = 32 * mm + l31;
        int p = (2 * ks + g) ^ l7;
        Bp[mm] = __builtin_bit_cast(bf16x8,
            *(const int4v*)(psR + mrow * 128 + p * 16));
      }
      #pragma unroll
      for (int t2 = 0; t2 < 2; ++t2) {
        accO[t2][0] = __builtin_amdgcn_mfma_f32_32x32x16_bf16(XfO[t2][ks], Bp[0], accO[t2][0], 0,0,0);
        accO[t2][1] = __builtin_amdgcn_mfma_f32_32x32x16_bf16(XfO[t2][ks], Bp[1], accO[t2][1], 0,0,0);
      }
    }
  }

  // ---- epilogue: PLAIN stores into private q-slab (single writer/elem) ----
  csacc += __shfl_xor(csacc, 32, 64);
  if (g == 0) csp[(size_t)(2 * q + a_sub) * NPTS + m0 + mloc] = csacc;
  float* np = nump + (size_t)q * (DFEAT * (size_t)NPTS);
  #pragma unroll
  for (int t2 = 0; t2 < 2; ++t2)
    #pragma unroll
    for (int mm = 0; mm < 2; ++mm)
      #pragma unroll
      for (int r = 0; r < 16; ++r) {
        int drow = 32 * (2 * w + t2) + (r & 3) + 8 * (r >> 2) + 4 * g;
        int mg   = m0 + 32 * mm + l31;
        np[(size_t)drow * NPTS + mg] = accO[t2][mm][r];
      }
}

// ---------------------------------------------------------------------------
// Combine. mode1: v = (sum of 4 num_p slabs) * (1 / sum of 8 cs_p slices)
//          -> yout ; mode0: v = src (initial fp32 X).
// Both: emit xaf + xbf frags. No zeroing (partials single-writer, fully
// overwritten each iteration). Reciprocal computed once per thread (nq is
// i-invariant), replacing 16 IEEE div chains.
// ---------------------------------------------------------------------------
__global__ __launch_bounds__(256) void ms_combine(
    const float* __restrict__ src, const float* __restrict__ csp,
    float* __restrict__ yout,
    uint16_t* __restrict__ xaf, uint16_t* __restrict__ xbf,
    const int mode)
{
  __shared__ uint16_t T[64][66];
  const int tid = threadIdx.x;
  const int n0 = blockIdx.x * 64;
  const int d0 = blockIdx.y * 64;

  f32x4 rinv;
  if (mode) {
    const int nq = tid & 15;
    f32x4 c = *(const f32x4*)(csp + n0 + nq * 4);
    #pragma unroll
    for (int s2 = 1; s2 < 8; ++s2)
      c += *(const f32x4*)(csp + (size_t)s2 * NPTS + n0 + nq * 4);
    rinv[0] = 1.0f / c[0]; rinv[1] = 1.0f / c[1];
    rinv[2] = 1.0f / c[2]; rinv[3] = 1.0f / c[3];
  }

  #pragma unroll
  for (int i = 0; i < 4; ++i) {
    int e  = tid + i * 256;              // float4 slot
    int dl = e >> 4, nq = e & 15;
    size_t idx = (size_t)(d0 + dl) * NPTS + (n0 + nq * 4);
    f32x4 v = *(const f32x4*)(src + idx);
    if (mode) {
      v += *(const f32x4*)(src + idx + (size_t)1 * DFEAT * NPTS);
      v += *(const f32x4*)(src + idx + (size_t)2 * DFEAT * NPTS);
      v += *(const f32x4*)(src + idx + (size_t)3 * DFEAT * NPTS);
      v *= rinv;
      *(f32x4*)(yout + idx) = v;
    }
    #pragma unroll
    for (int k = 0; k < 4; ++k) T[dl][nq * 4 + k] = f2bf(v[k]);
  }
  __syncthreads();

  char* xafc = (char*)xaf;
  char* xbfc = (char*)xbf;
  // xaf chunks: (nb, s, lane) -> T[s*8 + j][nb*32+lane]
  #pragma unroll
  for (int i = 0; i < 2; ++i) {
    int c  = tid + i * 256;
    int nb = c >> 8, s2 = (c >> 5) & 7, ln = c & 31;
    union { uint32_t u[4]; int4v v; } pk;
    #pragma unroll
    for (int k = 0; k < 4; ++k) {
      uint32_t lo = T[s2 * 8 + 2 * k][nb * 32 + ln];
      uint32_t hi = T[s2 * 8 + 2 * k + 1][nb * 32 + ln];
      pk.u[k] = lo | (hi << 16);
    }
    *(int4v*)(xafc + (size_t)(n0 / 32 + nb) * 16384 +
              (size_t)(d0 / 8 + s2) * 512 + ln * 16) = pk.v;
  }
  // xbf chunks: (db, u, lane) -> T[db*32+lane][u*8 + j]  (row-contiguous)
  #pragma unroll
  for (int i = 0; i < 2; ++i) {
    int c  = tid + i * 256;
    int db = c >> 8, uu = (c >> 5) & 7, ln = c & 31;
    const uint16_t* tr = &T[db * 32 + ln][uu * 8];
    union { uint32_t u[4]; int4v v; } pk;
    #pragma unroll
    for (int k = 0; k < 4; ++k)
      pk.u[k] = (uint32_t)tr[2 * k] | ((uint32_t)tr[2 * k + 1] << 16);
    *(int4v*)(xbfc + (size_t)(d0 / 32 + db) * 524288 +
              (size_t)(n0 / 8 + uu) * 512 + ln * 16) = pk.v;
  }
}

extern "C" void kernel_launch(void* const* d_in, const int* in_sizes, int n_in,
                              void* d_out, int out_size, void* d_ws, size_t ws_size,
                              hipStream_t stream)
{
  (void)in_sizes; (void)n_in; (void)out_size; (void)ws_size;
  const float* X = (const float*)d_in[0];
  float* out = (float*)d_out;
  char* ws = (char*)d_ws;
  // ws: [0,4M) xaf ; [4M,8M) xbf ; [8M,40M) num_p[4] ; [40M,+256K) cs_p[8]
  uint16_t* xaf  = (uint16_t*)(ws);
  uint16_t* xbf  = (uint16_t*)(ws + (4u << 20));
  float*    nump = (float*)   (ws + (8u << 20));
  float*    csp  = (float*)   (ws + (40u << 20));

  // no zeroing needed: every partial element is written by exactly one
  // thread each iteration before combine reads it.

  dim3 cgrid(NPTS / 64, DFEAT / 64);
  ms_combine<<<cgrid, 256, 0, stream>>>(X, nullptr, nullptr, xaf, xbf, 0);
  for (int it = 0; it < 3; ++it) {
    ms_fused<<<512, 256, 0, stream>>>(xaf, xbf, nump, csp);
    ms_combine<<<cgrid, 256, 0, stream>>>(nump, csp,
                                          out + (size_t)it * DFEAT * NPTS,
                                          xaf, xbf, 1);
  }
}